// Round 3
// baseline (349.112 us; speedup 1.0000x reference)
//
#include <hip/hip_runtime.h>

// ---------------------------------------------------------------------------
// SwitchMLP (top-1 MoE, SwiGLU) for MI355X / gfx950.  S=1024 B=4 DIM=768
// HID=2048 E=8, f32 in/out.
//
// All GEMM operands pre-staged in f16 MFMA fragment order; GEMM K-loops are
// pure global_load_dwordx4 -> v_mfma, register-double-buffered, no LDS.
//   convert: w1/w2/w3 f32 [K][N] -> swizzled f16 B-operand cells
//            (wave-tile = 8 k-rows x 256 n-cols; every global load instr is
//             1 KB fully contiguous; in-register 4x8 transpose; LDS-free)
//   router : f64 logits, argmax, per-expert token lists, max-prob
//   gather : X rows -> Ag (A-operand cells, zero-padded to 64-row tiles)
//   gemm1  : h = silu(A@W1)*(A@W2), epilogue LDS-transpose C->A layout -> Hs
//   gemm2  : out[tok] = bf16_rne(Hs@W3) * prob[tok]
//
// Fragment layouts (HW-validated in rounds 1-2):
//   A-op: lane l holds A[m=l&15][k=(l>>4)*8+j]   (cell = 16m x 32k = 512 f16)
//   B-op: lane l holds B[k=(l>>4)*8+j][n=l&15]   (cell = 32k x 16n = 512 f16)
//   C/D : lane l holds C[row=(l>>4)*4+r][col=l&15]
// ---------------------------------------------------------------------------

#define T_TOK 4096
#define DIM   768
#define HID   2048
#define NE    8
#define ECAP  1024           // per-expert token capacity (~24 sigma margin)

#define KB1 24               // DIM/32  k-cells, gemm1
#define NB1 128              // HID/16  n-cells, w1/w2
#define KB2 64               // HID/32  k-cells, gemm2
#define NB2 48               // DIM/16  n-cells, w3
#define MBC 64               // ECAP/16 m-cells per expert

typedef _Float16 f16x8 __attribute__((ext_vector_type(8)));
typedef float    f32x4 __attribute__((ext_vector_type(4)));

__device__ __forceinline__ float bf16_rne(float v) {
    unsigned u = __float_as_uint(v);
    unsigned r = (u + 0x7fffu + ((u >> 16) & 1u)) & 0xffff0000u;
    return __uint_as_float(r);
}

// ---------------------------------------------------------------------------
__global__ void moe_init_kernel(int* __restrict__ counts) {
    if (threadIdx.x < NE) counts[threadIdx.x] = 0;
}

// ---------------------------------------------------------------------------
// Convert+swizzle, streaming-read version.  One wave-tile = 8 k-rows x 256
// n-cols of one [K][N] f32 matrix.  Lane l owns cols 4l..4l+3 of the tile:
// each of the 8 row-loads is a wave-wide 1 KB CONTIGUOUS float4 instruction.
// In-register 4x8 transpose -> 4 f16x8 vectors = fragment lanes for cols
// c0..c0+3 (64 B contiguous per thread).  4 independent wave-tiles/block.
//   slab s (8 rows): kb = s>>2, fq = s&3;  col c: nb = c>>4, fr = c&15
//   dst lane offset = (fq*16 + fr) * 8 f16
// Per matrix-expert: w1/w2: 96 slabs x 8 segs = 768 tiles; w3: 256 slabs x 3
// segs = 768 tiles; 192 blocks each; grid = 24 * 192 = 4608.
__global__ __launch_bounds__(256) void moe_convert_kernel(
    const float* __restrict__ w1, const float* __restrict__ w2,
    const float* __restrict__ w3, _Float16* __restrict__ w1s,
    _Float16* __restrict__ w2s, _Float16* __restrict__ w3s)
{
    const int me  = blockIdx.x / 192;    // matrix-expert: 0..7 w1, 8..15 w2, 16..23 w3
    const int blk = blockIdx.x % 192;
    const int t = threadIdx.x, w = t >> 6, l = t & 63;
    const int tile = blk * 4 + w;

    const float* src; _Float16* dst; int N, KBc, s, seg;
    if (me < 8) {
        src = w1 + (size_t)me * DIM * HID; dst = w1s + (size_t)me * NB1 * KB1 * 512;
        N = HID; KBc = KB1; s = tile >> 3; seg = tile & 7;
    } else if (me < 16) {
        const int e = me - 8;
        src = w2 + (size_t)e * DIM * HID; dst = w2s + (size_t)e * NB1 * KB1 * 512;
        N = HID; KBc = KB1; s = tile >> 3; seg = tile & 7;
    } else {
        const int e = me - 16;
        src = w3 + (size_t)e * HID * DIM; dst = w3s + (size_t)e * NB2 * KB2 * 512;
        N = DIM; KBc = KB2; s = tile / 3; seg = tile % 3;
    }

    const float* p = src + (size_t)(s * 8) * N + seg * 256 + 4 * l;

    float4 v[8];
#pragma unroll
    for (int j = 0; j < 8; ++j) v[j] = *(const float4*)(p + (size_t)j * N);

    f16x8 h[4];
#pragma unroll
    for (int j = 0; j < 8; ++j) {
        h[0][j] = (_Float16)v[j].x;
        h[1][j] = (_Float16)v[j].y;
        h[2][j] = (_Float16)v[j].z;
        h[3][j] = (_Float16)v[j].w;
    }

    const int kb = s >> 2, fq = s & 3;
    const int c0 = seg * 256 + 4 * l;
#pragma unroll
    for (int q = 0; q < 4; ++q) {
        const int c = c0 + q;
        const int nb = c >> 4, fr = c & 15;
        *(f16x8*)(dst + ((size_t)(nb * KBc + kb)) * 512 + (fq * 16 + fr) * 8) = h[q];
    }
}

// ---------------------------------------------------------------------------
// One wave per token: f64 logits (argmax robustness), max softmax prob,
// atomic append to owning expert's list.
__global__ __launch_bounds__(256) void moe_router_kernel(
    const float* __restrict__ X, const float* __restrict__ rw,
    const float* __restrict__ rb, float* __restrict__ probs,
    int* __restrict__ counts, int* __restrict__ lists)
{
    const int t    = blockIdx.x * 4 + (threadIdx.x >> 6);
    const int lane = threadIdx.x & 63;
    const float* x = X + (size_t)t * DIM;

    float xv[12];
#pragma unroll
    for (int j = 0; j < 12; ++j) xv[j] = x[lane + j * 64];

    double lg[NE];
#pragma unroll
    for (int e = 0; e < NE; ++e) {
        double s = 0.0;
#pragma unroll
        for (int j = 0; j < 12; ++j)
            s += (double)xv[j] * (double)rw[(lane + j * 64) * NE + e];
#pragma unroll
        for (int off = 32; off >= 1; off >>= 1) s += __shfl_xor(s, off, 64);
        lg[e] = s + (double)rb[e];
    }

    if (lane == 0) {
        double m = lg[0]; int mi = 0;
#pragma unroll
        for (int e = 1; e < NE; ++e)
            if (lg[e] > m) { m = lg[e]; mi = e; }
        float sum = 0.f;
#pragma unroll
        for (int e = 0; e < NE; ++e) sum += expf((float)(lg[e] - m));
        probs[t] = 1.0f / sum;
        int pos = atomicAdd(&counts[mi], 1);
        lists[mi * T_TOK + pos] = t;
    }
}

// ---------------------------------------------------------------------------
// Gather X rows per expert into A-operand cells (f16), zero-padding rows
// beyond cnt up to the 64-row tile boundary.
__global__ __launch_bounds__(256) void moe_gather_kernel(
    const float* __restrict__ X, const int* __restrict__ lists,
    const int* __restrict__ counts, _Float16* __restrict__ Ag)
{
    const int e = blockIdx.z;
    int cnt = counts[e]; if (cnt > ECAP) cnt = ECAP;
    const int mgrp = blockIdx.y;
    if (mgrp * 64 >= ((cnt + 63) & ~63)) return;
    const int t = threadIdx.x, w = t >> 6, l = t & 63;
    const int mb = mgrp * 4 + w;
    const int m  = mb * 16 + (l & 15);
    const bool valid = (m < cnt);
    const int tok = valid ? lists[e * T_TOK + m] : 0;
    const float* xr = X + (size_t)tok * DIM + (l >> 4) * 8;
#pragma unroll
    for (int i = 0; i < 4; ++i) {
        const int kb = blockIdx.x * 4 + i;
        float4 a = make_float4(0.f, 0.f, 0.f, 0.f), b = a;
        if (valid) {
            a = *(const float4*)(xr + kb * 32);
            b = *(const float4*)(xr + kb * 32 + 4);
        }
        f16x8 h;
        h[0] = (_Float16)a.x; h[1] = (_Float16)a.y; h[2] = (_Float16)a.z; h[3] = (_Float16)a.w;
        h[4] = (_Float16)b.x; h[5] = (_Float16)b.y; h[6] = (_Float16)b.z; h[7] = (_Float16)b.w;
        *(f16x8*)(Ag + ((size_t)(e * MBC + mb) * KB1 + kb) * 512 + l * 8) = h;
    }
}

// ---------------------------------------------------------------------------
// GEMM1: block = 128m x 64n (both W1,W2), wave = 64m x 32n. Register
// double-buffered K-loop (no LDS, no barriers). Epilogue: silu(h1)*h2 -> f16,
// C->A layout via per-wave LDS, write Hs cells.
__global__ __launch_bounds__(256, 3) void moe_gemm1_kernel(
    const _Float16* __restrict__ Ag, const _Float16* __restrict__ w1s,
    const _Float16* __restrict__ w2s, const int* __restrict__ counts,
    _Float16* __restrict__ Hs)
{
    const int e = blockIdx.z;
    int cnt = counts[e]; if (cnt > ECAP) cnt = ECAP;
    const int by = blockIdx.y, bx = blockIdx.x;   // by: 128m, bx: 64n
    if (by * 128 >= cnt) return;
    const int t = threadIdx.x, w = t >> 6, l = t & 63;
    const int wm = w & 1, wn = w >> 1;

    const _Float16* Ab  = Ag + ((size_t)((e * MBC + by * 8 + wm * 4) * KB1)) * 512 + l * 8;
    const int nb0 = e * NB1 + bx * 4 + wn * 2;
    const _Float16* B1b = w1s + ((size_t)nb0 * KB1) * 512 + l * 8;
    const _Float16* B2b = w2s + ((size_t)nb0 * KB1) * 512 + l * 8;

    f32x4 acc1[4][2], acc2[4][2];
    const f32x4 zero = {0.f, 0.f, 0.f, 0.f};
#pragma unroll
    for (int i = 0; i < 4; ++i)
#pragma unroll
        for (int j = 0; j < 2; ++j) { acc1[i][j] = zero; acc2[i][j] = zero; }

    f16x8 a0[4], p0[2], q0[2], a1[4], p1[2], q1[2];

    auto LD = [&](f16x8* a, f16x8* p, f16x8* q, int kb) {
#pragma unroll
        for (int i = 0; i < 4; ++i)
            a[i] = *(const f16x8*)(Ab + ((size_t)(i * KB1 + kb)) * 512);
#pragma unroll
        for (int j = 0; j < 2; ++j) {
            p[j] = *(const f16x8*)(B1b + ((size_t)(j * KB1 + kb)) * 512);
            q[j] = *(const f16x8*)(B2b + ((size_t)(j * KB1 + kb)) * 512);
        }
    };
    auto FM = [&](const f16x8* a, const f16x8* p, const f16x8* q) {
#pragma unroll
        for (int i = 0; i < 4; ++i)
#pragma unroll
            for (int j = 0; j < 2; ++j) {
                acc1[i][j] = __builtin_amdgcn_mfma_f32_16x16x32_f16(a[i], p[j], acc1[i][j], 0, 0, 0);
                acc2[i][j] = __builtin_amdgcn_mfma_f32_16x16x32_f16(a[i], q[j], acc2[i][j], 0, 0, 0);
            }
    };

    LD(a0, p0, q0, 0);
    int kb = 0;
    for (; kb + 2 < KB1; kb += 2) {
        LD(a1, p1, q1, kb + 1);
        FM(a0, p0, q0);
        LD(a0, p0, q0, kb + 2);
        FM(a1, p1, q1);
    }
    LD(a1, p1, q1, kb + 1);
    FM(a0, p0, q0);
    FM(a1, p1, q1);

    // epilogue: silu(h1)*h2 -> f16; C-layout -> A-layout via per-wave LDS
    __shared__ _Float16 Ep[4][64 * 40];
    const int fq = l >> 4, fr = l & 15;
#pragma unroll
    for (int i = 0; i < 4; ++i)
#pragma unroll
        for (int j = 0; j < 2; ++j)
#pragma unroll
            for (int r = 0; r < 4; ++r) {
                const float h1 = acc1[i][j][r], h2 = acc2[i][j][r];
                const float s  = h1 / (1.f + __expf(-h1)) * h2;
                Ep[w][(i * 16 + fq * 4 + r) * 40 + j * 16 + fr] = (_Float16)s;
            }
    __syncthreads();
    const int kbH = bx * 2 + wn;         // this wave's 32-wide hid cell
#pragma unroll
    for (int i = 0; i < 4; ++i) {
        f16x8 v = *(const f16x8*)&Ep[w][(i * 16 + fr) * 40 + fq * 8];
        *(f16x8*)(Hs + ((size_t)((e * MBC + by * 8 + wm * 4 + i) * KB2 + kbH)) * 512 + l * 8) = v;
    }
}

// ---------------------------------------------------------------------------
// GEMM2: block = 64m x 128n, wave = 64m x 32n, K=2048, register
// double-buffered. Epilogue: bf16_rne(acc) * prob, scatter f32 by token.
__global__ __launch_bounds__(256, 4) void moe_gemm2_kernel(
    const _Float16* __restrict__ Hs, const _Float16* __restrict__ w3s,
    const int* __restrict__ lists, const int* __restrict__ counts,
    const float* __restrict__ probs, float* __restrict__ out)
{
    const int e = blockIdx.z;
    int cnt = counts[e]; if (cnt > ECAP) cnt = ECAP;
    const int by = blockIdx.y, bx = blockIdx.x;   // by: 64m, bx: 128n
    if (by * 64 >= cnt) return;
    const int t = threadIdx.x, w = t >> 6, l = t & 63;

    const _Float16* Ab = Hs + ((size_t)((e * MBC + by * 4) * KB2)) * 512 + l * 8;
    const int nb0 = e * NB2 + bx * 8 + w * 2;
    const _Float16* Bb = w3s + ((size_t)nb0 * KB2) * 512 + l * 8;

    f32x4 acc[4][2];
    const f32x4 zero = {0.f, 0.f, 0.f, 0.f};
#pragma unroll
    for (int i = 0; i < 4; ++i) { acc[i][0] = zero; acc[i][1] = zero; }

    f16x8 a0[4], b0[2], a1[4], b1[2];

    auto LD = [&](f16x8* a, f16x8* b, int kb) {
#pragma unroll
        for (int i = 0; i < 4; ++i)
            a[i] = *(const f16x8*)(Ab + ((size_t)(i * KB2 + kb)) * 512);
#pragma unroll
        for (int j = 0; j < 2; ++j)
            b[j] = *(const f16x8*)(Bb + ((size_t)(j * KB2 + kb)) * 512);
    };
    auto FM = [&](const f16x8* a, const f16x8* b) {
#pragma unroll
        for (int i = 0; i < 4; ++i)
#pragma unroll
            for (int j = 0; j < 2; ++j)
                acc[i][j] = __builtin_amdgcn_mfma_f32_16x16x32_f16(a[i], b[j], acc[i][j], 0, 0, 0);
    };

    LD(a0, b0, 0);
    int kb = 0;
    for (; kb + 2 < KB2; kb += 2) {
        LD(a1, b1, kb + 1);
        FM(a0, b0);
        LD(a0, b0, kb + 2);
        FM(a1, b1);
    }
    LD(a1, b1, kb + 1);
    FM(a0, b0);
    FM(a1, b1);

    const int* list = lists + e * T_TOK;
    const int fq = l >> 4, fr = l & 15;
    const int c0 = bx * 128 + w * 32;
#pragma unroll
    for (int i = 0; i < 4; ++i)
#pragma unroll
        for (int r = 0; r < 4; ++r) {
            const int m = by * 64 + i * 16 + fq * 4 + r;
            if (m < cnt) {
                const int tok = list[m];
                const float pb = probs[tok];
                float* orow = out + (size_t)tok * DIM + c0 + fr;
                orow[0]  = bf16_rne(acc[i][0][r]) * pb;
                orow[16] = bf16_rne(acc[i][1][r]) * pb;
            }
        }
}

// ---------------------------------------------------------------------------
extern "C" void kernel_launch(void* const* d_in, const int* in_sizes, int n_in,
                              void* d_out, int out_size, void* d_ws, size_t ws_size,
                              hipStream_t stream) {
    const float* X  = (const float*)d_in[0];
    const float* rw = (const float*)d_in[1];
    const float* rb = (const float*)d_in[2];
    const float* w1 = (const float*)d_in[3];
    const float* w2 = (const float*)d_in[4];
    const float* w3 = (const float*)d_in[5];
    float* out = (float*)d_out;

    // workspace layout (bytes); total ~121.6 MB
    char* ws = (char*)d_ws;
    int*      counts = (int*)(ws + 0);
    int*      lists  = (int*)(ws + 256);
    float*    probs  = (float*)(ws + 131328);
    const size_t WSZ = 25165824;  // each swizzled weight: 8*NB*KB*512*2 B
    _Float16* w1s = (_Float16*)(ws + 147712);
    _Float16* w2s = (_Float16*)(ws + 147712 + WSZ);
    _Float16* w3s = (_Float16*)(ws + 147712 + 2 * WSZ);
    _Float16* Ag  = (_Float16*)(ws + 147712 + 3 * WSZ);              // 12.6 MB
    _Float16* Hs  = (_Float16*)(ws + 147712 + 3 * WSZ + 12582912);   // 33.6 MB

    hipLaunchKernelGGL(moe_init_kernel, dim3(1), dim3(64), 0, stream, counts);
    hipLaunchKernelGGL(moe_convert_kernel, dim3(4608), dim3(256), 0, stream,
                       w1, w2, w3, w1s, w2s, w3s);
    hipLaunchKernelGGL(moe_router_kernel, dim3(T_TOK / 4), dim3(256), 0, stream,
                       X, rw, rb, probs, counts, lists);
    hipLaunchKernelGGL(moe_gather_kernel, dim3(6, 16, 8), dim3(256), 0, stream,
                       X, lists, counts, Ag);
    hipLaunchKernelGGL(moe_gemm1_kernel, dim3(32, 8, 8), dim3(256), 0, stream,
                       Ag, w1s, w2s, counts, Hs);
    hipLaunchKernelGGL(moe_gemm2_kernel, dim3(6, 16, 8), dim3(256), 0, stream,
                       Hs, w3s, lists, counts, probs, out);
}

// Round 4
// 323.274 us; speedup vs baseline: 1.0799x; 1.0799x over previous
//
#include <hip/hip_runtime.h>

// ---------------------------------------------------------------------------
// SwitchMLP (top-1 MoE, SwiGLU) for MI355X / gfx950.  S=1024 B=4 DIM=768
// HID=2048 E=8, f32 in/out.
//
// GEMM operands pre-staged in f16 MFMA fragment order (1 KB "cells").
//   convert: w1/w2/w3 f32 [K][N] -> swizzled f16 B-operand cells (round-0
//            LDS variant — best measured of 3 structures, 64.5 us)
//   router : f64 logits, argmax, per-expert token lists, max-prob
//   gather : X rows -> Ag (A-operand cells, zero-padded to 64-row tiles)
//   gemm1  : h = silu(A@W1)*(A@W2); LDS-staged operands (block-shared),
//            double-buffered, 1 barrier/K-step; epilogue C->A layout -> Hs
//   gemm2  : out[tok] = bf16_rne(Hs@W3) * prob[tok]; LDS-staged, 2 K-cells
//            per barrier
//
// Fragment layouts (HW-validated):
//   A-op: lane l holds A[m=l&15][k=(l>>4)*8+j]   (cell = 16m x 32k = 512 f16)
//   B-op: lane l holds B[k=(l>>4)*8+j][n=l&15]   (cell = 32k x 16n = 512 f16)
//   C/D : lane l holds C[row=(l>>4)*4+r][col=l&15]
// Cells are 1 KB contiguous -> LDS staging is linear lane*16B (conflict-free).
// ---------------------------------------------------------------------------

#define T_TOK 4096
#define DIM   768
#define HID   2048
#define NE    8
#define ECAP  1024           // per-expert token capacity (~24 sigma margin)

#define KB1 24               // DIM/32  k-cells, gemm1
#define NB1 128              // HID/16  n-cells, w1/w2
#define KB2 64               // HID/32  k-cells, gemm2
#define NB2 48               // DIM/16  n-cells, w3
#define MBC 64               // ECAP/16 m-cells per expert

typedef _Float16 f16x8 __attribute__((ext_vector_type(8)));
typedef float    f32x4 __attribute__((ext_vector_type(4)));

__device__ __forceinline__ float bf16_rne(float v) {
    unsigned u = __float_as_uint(v);
    unsigned r = (u + 0x7fffu + ((u >> 16) & 1u)) & 0xffff0000u;
    return __uint_as_float(r);
}

// ---------------------------------------------------------------------------
__global__ void moe_init_kernel(int* __restrict__ counts) {
    if (threadIdx.x < NE) counts[threadIdx.x] = 0;
}

// ---------------------------------------------------------------------------
// Convert+swizzle one 64k x 128n tile into B-operand cells (round-0 variant).
// LDS f32 [k][n] stride 130 (=2 mod 4): float2 writes and b32 column reads
// are both uniform <=2-way on banks. 8 float4 global loads/thread for MLP.
__global__ __launch_bounds__(256) void moe_convert_kernel(
    const float* __restrict__ w1, const float* __restrict__ w2,
    const float* __restrict__ w3, _Float16* __restrict__ w1s,
    _Float16* __restrict__ w2s, _Float16* __restrict__ w3s)
{
    const int bid = blockIdx.x;          // 0..4607
    const float* src; _Float16* dst; int N, KBc, ngrp, kgrp;
    if (bid < 1536) {
        const int e = bid / 192, tile = bid % 192;
        src = w1 + (size_t)e * DIM * HID; dst = w1s + (size_t)e * NB1 * KB1 * 512;
        N = HID; KBc = KB1; ngrp = tile & 15; kgrp = tile >> 4;
    } else if (bid < 3072) {
        const int r = bid - 1536, e = r / 192, tile = r % 192;
        src = w2 + (size_t)e * DIM * HID; dst = w2s + (size_t)e * NB1 * KB1 * 512;
        N = HID; KBc = KB1; ngrp = tile & 15; kgrp = tile >> 4;
    } else {
        const int r = bid - 3072, e = r / 192, tile = r % 192;
        src = w3 + (size_t)e * HID * DIM; dst = w3s + (size_t)e * NB2 * KB2 * 512;
        N = DIM; KBc = KB2; ngrp = tile % 6; kgrp = tile / 6;
    }

    __shared__ float Lt[64 * 130];
    const int t  = threadIdx.x;
    const int c4 = (t & 31) * 4;         // f32 col within 128
    const int r0 = (t >> 5) * 8;         // first of 8 k-rows
    const float* p = src + (size_t)(kgrp * 64 + r0) * N + ngrp * 128 + c4;
    float4 v[8];
#pragma unroll
    for (int j = 0; j < 8; ++j) v[j] = *(const float4*)(p + (size_t)j * N);
#pragma unroll
    for (int j = 0; j < 8; ++j) {
        float* row = &Lt[(r0 + j) * 130 + c4];
        *(float2*)(row)     = make_float2(v[j].x, v[j].y);
        *(float2*)(row + 2) = make_float2(v[j].z, v[j].w);
    }
    __syncthreads();

    const int l = t & 63, w = t >> 6;
    const int fr = l & 15, fq = l >> 4;
#pragma unroll
    for (int i = 0; i < 4; ++i) {
        const int cell = w * 4 + i;      // 16 cells: 2 kbl x 8 nbl
        const int kbl = cell >> 3, nbl = cell & 7;
        f16x8 h;
#pragma unroll
        for (int j = 0; j < 8; ++j)
            h[j] = (_Float16)Lt[(kbl * 32 + fq * 8 + j) * 130 + nbl * 16 + fr];
        const int nb = ngrp * 8 + nbl, kb = kgrp * 2 + kbl;
        *(f16x8*)(dst + ((size_t)nb * KBc + kb) * 512 + l * 8) = h;
    }
}

// ---------------------------------------------------------------------------
// One wave per token: f64 logits (argmax robustness), max softmax prob,
// atomic append to owning expert's list.
__global__ __launch_bounds__(256) void moe_router_kernel(
    const float* __restrict__ X, const float* __restrict__ rw,
    const float* __restrict__ rb, float* __restrict__ probs,
    int* __restrict__ counts, int* __restrict__ lists)
{
    const int t    = blockIdx.x * 4 + (threadIdx.x >> 6);
    const int lane = threadIdx.x & 63;
    const float* x = X + (size_t)t * DIM;

    float xv[12];
#pragma unroll
    for (int j = 0; j < 12; ++j) xv[j] = x[lane + j * 64];

    double lg[NE];
#pragma unroll
    for (int e = 0; e < NE; ++e) {
        double s = 0.0;
#pragma unroll
        for (int j = 0; j < 12; ++j)
            s += (double)xv[j] * (double)rw[(lane + j * 64) * NE + e];
#pragma unroll
        for (int off = 32; off >= 1; off >>= 1) s += __shfl_xor(s, off, 64);
        lg[e] = s + (double)rb[e];
    }

    if (lane == 0) {
        double m = lg[0]; int mi = 0;
#pragma unroll
        for (int e = 1; e < NE; ++e)
            if (lg[e] > m) { m = lg[e]; mi = e; }
        float sum = 0.f;
#pragma unroll
        for (int e = 0; e < NE; ++e) sum += expf((float)(lg[e] - m));
        probs[t] = 1.0f / sum;
        int pos = atomicAdd(&counts[mi], 1);
        lists[mi * T_TOK + pos] = t;
    }
}

// ---------------------------------------------------------------------------
// Gather X rows per expert into A-operand cells (f16), zero-padding rows
// beyond cnt up to the 64-row tile boundary.
__global__ __launch_bounds__(256) void moe_gather_kernel(
    const float* __restrict__ X, const int* __restrict__ lists,
    const int* __restrict__ counts, _Float16* __restrict__ Ag)
{
    const int e = blockIdx.z;
    int cnt = counts[e]; if (cnt > ECAP) cnt = ECAP;
    const int mgrp = blockIdx.y;
    if (mgrp * 64 >= ((cnt + 63) & ~63)) return;
    const int t = threadIdx.x, w = t >> 6, l = t & 63;
    const int mb = mgrp * 4 + w;
    const int m  = mb * 16 + (l & 15);
    const bool valid = (m < cnt);
    const int tok = valid ? lists[e * T_TOK + m] : 0;
    const float* xr = X + (size_t)tok * DIM + (l >> 4) * 8;
#pragma unroll
    for (int i = 0; i < 4; ++i) {
        const int kb = blockIdx.x * 4 + i;
        float4 a = make_float4(0.f, 0.f, 0.f, 0.f), b = a;
        if (valid) {
            a = *(const float4*)(xr + kb * 32);
            b = *(const float4*)(xr + kb * 32 + 4);
        }
        f16x8 h;
        h[0] = (_Float16)a.x; h[1] = (_Float16)a.y; h[2] = (_Float16)a.z; h[3] = (_Float16)a.w;
        h[4] = (_Float16)b.x; h[5] = (_Float16)b.y; h[6] = (_Float16)b.z; h[7] = (_Float16)b.w;
        *(f16x8*)(Ag + ((size_t)(e * MBC + mb) * KB1 + kb) * 512 + l * 8) = h;
    }
}

// ---------------------------------------------------------------------------
// GEMM1: block = 128m x 64n (both W1,W2), wave = 64m x 32n.  Per K-step the
// block stages 16 cells (8 A + 4 W1 + 4 W2 = 16 KB) into LDS (wave w stages
// cells 4w..4w+3, linear lane*16B), double-buffered, ONE barrier per step.
// Global prefetch for step kb+1 is issued AFTER the barrier so it stays in
// flight under ds_read+MFMA (compiler drains vmcnt before s_barrier).
// Epilogue: silu(h1)*h2 -> f16, C->A layout via per-wave LDS, write Hs cells.
__global__ __launch_bounds__(256, 3) void moe_gemm1_kernel(
    const _Float16* __restrict__ Ag, const _Float16* __restrict__ w1s,
    const _Float16* __restrict__ w2s, const int* __restrict__ counts,
    _Float16* __restrict__ Hs)
{
    const int e = blockIdx.z;
    int cnt = counts[e]; if (cnt > ECAP) cnt = ECAP;
    const int by = blockIdx.y, bx = blockIdx.x;   // by: 128m, bx: 64n
    if (by * 128 >= cnt) return;
    const int t = threadIdx.x, w = t >> 6, l = t & 63;
    const int wm = w & 1, wn = w >> 1;

    __shared__ _Float16 Ls[2][16 * 512];          // 32 KB staging
    __shared__ _Float16 Ep[4][64 * 40];           // 20 KB epilogue transpose

    // staging sources: wave w owns cells 4w..4w+3
    //   cells 0-7: A (m-cells by*8+c); 8-11: W1 n-cells bx*4+(c-8); 12-15: W2
    const int c0s = w * 4;
    const _Float16* gsrc[4];
#pragma unroll
    for (int i = 0; i < 4; ++i) {
        const int c = c0s + i;
        if (c < 8)
            gsrc[i] = Ag  + ((size_t)((e * MBC + by * 8 + c) * KB1)) * 512;
        else if (c < 12)
            gsrc[i] = w1s + ((size_t)((e * NB1 + bx * 4 + (c - 8)) * KB1)) * 512;
        else
            gsrc[i] = w2s + ((size_t)((e * NB1 + bx * 4 + (c - 12)) * KB1)) * 512;
        gsrc[i] += (size_t)l * 8;
    }

    f32x4 acc1[4][2], acc2[4][2];
    const f32x4 zero = {0.f, 0.f, 0.f, 0.f};
#pragma unroll
    for (int i = 0; i < 4; ++i)
#pragma unroll
        for (int j = 0; j < 2; ++j) { acc1[i][j] = zero; acc2[i][j] = zero; }

    f16x8 st[4];
    auto G = [&](int kb) {
#pragma unroll
        for (int i = 0; i < 4; ++i)
            st[i] = *(const f16x8*)(gsrc[i] + (size_t)kb * 512);
    };

    G(0);
    for (int kb = 0; kb < KB1; ++kb) {
        _Float16* Lb = &Ls[kb & 1][0];
#pragma unroll
        for (int i = 0; i < 4; ++i)
            *(f16x8*)(Lb + (c0s + i) * 512 + l * 8) = st[i];
        __syncthreads();
        if (kb + 1 < KB1) G(kb + 1);              // in flight under compute

        f16x8 a[4], p[2], q[2];
#pragma unroll
        for (int i = 0; i < 4; ++i)
            a[i] = *(const f16x8*)(Lb + (wm * 4 + i) * 512 + l * 8);
#pragma unroll
        for (int j = 0; j < 2; ++j) {
            p[j] = *(const f16x8*)(Lb + (8  + wn * 2 + j) * 512 + l * 8);
            q[j] = *(const f16x8*)(Lb + (12 + wn * 2 + j) * 512 + l * 8);
        }
#pragma unroll
        for (int i = 0; i < 4; ++i)
#pragma unroll
            for (int j = 0; j < 2; ++j) {
                acc1[i][j] = __builtin_amdgcn_mfma_f32_16x16x32_f16(a[i], p[j], acc1[i][j], 0, 0, 0);
                acc2[i][j] = __builtin_amdgcn_mfma_f32_16x16x32_f16(a[i], q[j], acc2[i][j], 0, 0, 0);
            }
    }

    // epilogue: silu(h1)*h2 -> f16; C-layout -> A-layout via per-wave LDS
    const int fq = l >> 4, fr = l & 15;
#pragma unroll
    for (int i = 0; i < 4; ++i)
#pragma unroll
        for (int j = 0; j < 2; ++j)
#pragma unroll
            for (int r = 0; r < 4; ++r) {
                const float h1 = acc1[i][j][r], h2 = acc2[i][j][r];
                const float s  = h1 / (1.f + __expf(-h1)) * h2;
                Ep[w][(i * 16 + fq * 4 + r) * 40 + j * 16 + fr] = (_Float16)s;
            }
    __syncthreads();
    const int kbH = bx * 2 + wn;         // this wave's 32-wide hid cell
#pragma unroll
    for (int i = 0; i < 4; ++i) {
        f16x8 v = *(const f16x8*)&Ep[w][(i * 16 + fr) * 40 + fq * 8];
        *(f16x8*)(Hs + ((size_t)((e * MBC + by * 8 + wm * 4 + i) * KB2 + kbH)) * 512 + l * 8) = v;
    }
}

// ---------------------------------------------------------------------------
// GEMM2: block = 64m x 128n, wave = 64m x 32n, K=2048.  Per barrier the block
// stages 2 K-cells worth of operands (2 x (4 A + 8 W3) = 24 KB) into LDS
// (wave w stages cells {u*12 + 3w .. 3w+2}), double-buffered, one barrier
// per 2 K-steps.  Epilogue: bf16_rne(acc) * prob, scatter f32 by token.
__global__ __launch_bounds__(256, 3) void moe_gemm2_kernel(
    const _Float16* __restrict__ Hs, const _Float16* __restrict__ w3s,
    const int* __restrict__ lists, const int* __restrict__ counts,
    const float* __restrict__ probs, float* __restrict__ out)
{
    const int e = blockIdx.z;
    int cnt = counts[e]; if (cnt > ECAP) cnt = ECAP;
    const int by = blockIdx.y, bx = blockIdx.x;   // by: 64m, bx: 128n
    if (by * 64 >= cnt) return;
    const int t = threadIdx.x, w = t >> 6, l = t & 63;

    __shared__ _Float16 Ls[2][24 * 512];          // 48 KB staging

    // staging sources: wave w owns cells 3w..3w+2 (of 12 per K-cell)
    //   cells 0-3: A (m-cells by*4+c); 4-11: W3 n-cells bx*8+(c-4)
    const int c0s = w * 3;
    const _Float16* gsrc[3];
#pragma unroll
    for (int i = 0; i < 3; ++i) {
        const int c = c0s + i;
        if (c < 4)
            gsrc[i] = Hs  + ((size_t)((e * MBC + by * 4 + c) * KB2)) * 512;
        else
            gsrc[i] = w3s + ((size_t)((e * NB2 + bx * 8 + (c - 4)) * KB2)) * 512;
        gsrc[i] += (size_t)l * 8;
    }

    f32x4 acc[4][2];
    const f32x4 zero = {0.f, 0.f, 0.f, 0.f};
#pragma unroll
    for (int i = 0; i < 4; ++i) { acc[i][0] = zero; acc[i][1] = zero; }

    f16x8 st[6];
    auto G = [&](int kb0) {
#pragma unroll
        for (int u = 0; u < 2; ++u)
#pragma unroll
            for (int i = 0; i < 3; ++i)
                st[u * 3 + i] = *(const f16x8*)(gsrc[i] + (size_t)(kb0 + u) * 512);
    };

    G(0);
    for (int s = 0; s < KB2 / 2; ++s) {
        _Float16* Lb = &Ls[s & 1][0];
#pragma unroll
        for (int u = 0; u < 2; ++u)
#pragma unroll
            for (int i = 0; i < 3; ++i)
                *(f16x8*)(Lb + (u * 12 + c0s + i) * 512 + l * 8) = st[u * 3 + i];
        __syncthreads();
        if (s + 1 < KB2 / 2) G(2 * (s + 1));      // in flight under compute

#pragma unroll
        for (int u = 0; u < 2; ++u) {
            f16x8 a[4], b[2];
#pragma unroll
            for (int i = 0; i < 4; ++i)
                a[i] = *(const f16x8*)(Lb + (u * 12 + i) * 512 + l * 8);
#pragma unroll
            for (int j = 0; j < 2; ++j)
                b[j] = *(const f16x8*)(Lb + (u * 12 + 4 + w * 2 + j) * 512 + l * 8);
#pragma unroll
            for (int i = 0; i < 4; ++i)
#pragma unroll
                for (int j = 0; j < 2; ++j)
                    acc[i][j] = __builtin_amdgcn_mfma_f32_16x16x32_f16(a[i], b[j], acc[i][j], 0, 0, 0);
        }
    }

    const int* list = lists + e * T_TOK;
    const int fq = l >> 4, fr = l & 15;
    const int c0 = bx * 128 + w * 32;
#pragma unroll
    for (int i = 0; i < 4; ++i)
#pragma unroll
        for (int r = 0; r < 4; ++r) {
            const int m = by * 64 + i * 16 + fq * 4 + r;
            if (m < cnt) {
                const int tok = list[m];
                const float pb = probs[tok];
                float* orow = out + (size_t)tok * DIM + c0 + fr;
                orow[0]  = bf16_rne(acc[i][0][r]) * pb;
                orow[16] = bf16_rne(acc[i][1][r]) * pb;
            }
        }
}

// ---------------------------------------------------------------------------
extern "C" void kernel_launch(void* const* d_in, const int* in_sizes, int n_in,
                              void* d_out, int out_size, void* d_ws, size_t ws_size,
                              hipStream_t stream) {
    const float* X  = (const float*)d_in[0];
    const float* rw = (const float*)d_in[1];
    const float* rb = (const float*)d_in[2];
    const float* w1 = (const float*)d_in[3];
    const float* w2 = (const float*)d_in[4];
    const float* w3 = (const float*)d_in[5];
    float* out = (float*)d_out;

    // workspace layout (bytes); total ~121.6 MB
    char* ws = (char*)d_ws;
    int*      counts = (int*)(ws + 0);
    int*      lists  = (int*)(ws + 256);
    float*    probs  = (float*)(ws + 131328);
    const size_t WSZ = 25165824;  // each swizzled weight: 8*NB*KB*512*2 B
    _Float16* w1s = (_Float16*)(ws + 147712);
    _Float16* w2s = (_Float16*)(ws + 147712 + WSZ);
    _Float16* w3s = (_Float16*)(ws + 147712 + 2 * WSZ);
    _Float16* Ag  = (_Float16*)(ws + 147712 + 3 * WSZ);              // 12.6 MB
    _Float16* Hs  = (_Float16*)(ws + 147712 + 3 * WSZ + 12582912);   // 33.6 MB

    hipLaunchKernelGGL(moe_init_kernel, dim3(1), dim3(64), 0, stream, counts);
    hipLaunchKernelGGL(moe_convert_kernel, dim3(4608), dim3(256), 0, stream,
                       w1, w2, w3, w1s, w2s, w3s);
    hipLaunchKernelGGL(moe_router_kernel, dim3(T_TOK / 4), dim3(256), 0, stream,
                       X, rw, rb, probs, counts, lists);
    hipLaunchKernelGGL(moe_gather_kernel, dim3(6, 16, 8), dim3(256), 0, stream,
                       X, lists, counts, Ag);
    hipLaunchKernelGGL(moe_gemm1_kernel, dim3(32, 8, 8), dim3(256), 0, stream,
                       Ag, w1s, w2s, counts, Hs);
    hipLaunchKernelGGL(moe_gemm2_kernel, dim3(6, 16, 8), dim3(256), 0, stream,
                       Hs, w3s, lists, counts, probs, out);
}